// Round 2
// baseline (55571.906 us; speedup 1.0000x reference)
//
#include <hip/hip_runtime.h>
#include <hip/hip_cooperative_groups.h>
#include <stdint.h>

namespace cg = cooperative_groups;

#define TT 128
#define BB 64
#define DD 1024
#define G3 3072
#define NBLK 240

typedef unsigned short u16;
typedef unsigned int u32;
typedef __attribute__((ext_vector_type(8))) short bf16x8;
typedef __attribute__((ext_vector_type(4))) short s16x4;
typedef __attribute__((ext_vector_type(4))) float f32x4;

__device__ __forceinline__ float b2f(u16 h){ u32 u = ((u32)h)<<16; float f; __builtin_memcpy(&f,&u,4); return f; }
__device__ __forceinline__ u16 f2b(float f){ u32 u; __builtin_memcpy(&u,&f,4); u = (u + 0x7fffu + ((u>>16)&1u))>>16; return (u16)u; }
__device__ __forceinline__ float sigm(float x){ return 1.f/(1.f+__expf(-x)); }
__device__ __forceinline__ float tanh_(float x){
  if (x > 10.f) return 1.f;
  if (x < -10.f) return -1.f;
  float e = __expf(2.f*x); return (e-1.f)/(e+1.f);
}

__device__ __forceinline__ bf16x8 load8(const u16* p){ return *(const bf16x8*)p; }
__device__ __forceinline__ bf16x8 load8(const float* p){
  f32x4 lo = *(const f32x4*)p;
  f32x4 hi = *(const f32x4*)(p + 4);
  bf16x8 r;
  #pragma unroll
  for (int i = 0; i < 4; ++i) { r[i] = (short)f2b(lo[i]); r[i+4] = (short)f2b(hi[i]); }
  return r;
}

struct DPar {
  const float *Wg,*Whg,*Wp,*Whp,*We,*Whe;   // fp32 original weights (fallback path)
  const u16 *A1,*A2,*A3,*A4,*A5,*A6;        // bf16 weight copies (full path)
  const float* feat;                         // fp32 features (T,B,DM)
  u16 *ghist,*cb,*qselb,*qnewb,*eb;
  float *scores,*parties,*gf,*ef;
  float *GIGa,*GIGb,*GHG,*GHP,*GIE,*GIPa,*GIPb,*GHE;
  const float *bihg,*bhhg,*bihp,*bhhp,*bihe,*bhhe,*watt;
  const int* spk;
  float* out;
};

// ---- 64x64 output-tile GEMM, K=1024: C[64 rows][G3 cols] tile = A[64][K] * W[n][k]^T
// A row-major (ldA elems), W row-major (ldW elems), rows n0..n0+63, cols k0..k0+1023.
// LDS XOR-swizzle: LDS[r][c16 ^ (r&7)] holds 16B-group c16 of row r.
template<typename TA, typename TW>
__device__ __attribute__((noinline)) void gemm64(
    const TA* __restrict__ A, int ldA,
    const TW* __restrict__ W, int ldW, int k0, int n0,
    float* __restrict__ C, u16* lds) {
  const int tid  = threadIdx.x;
  const int lane = tid & 63;
  const int wave = tid >> 6;
  const int wm = (wave >> 1) * 32;
  const int wn = (wave & 1) * 32;
  const int l15 = lane & 15;
  const int l4  = lane >> 4;
  const int swzr = l15 & 7;
  const int r0 = tid >> 3, c0 = tid & 7;
  const int r1 = r0 + 32;
  const int sw0 = (c0 ^ (r0 & 7)) * 8;
  const int sw1 = (c0 ^ (r1 & 7)) * 8;
  u16* As0 = lds;          // [2][64][64] bf16 double-buffered
  u16* Bs0 = lds + 8192;
  const TA* Arow0 = A + (size_t)r0 * ldA;
  const TA* Arow1 = A + (size_t)r1 * ldA;
  const TW* Wrow0 = W + (size_t)(n0 + r0) * ldW + k0;
  const TW* Wrow1 = W + (size_t)(n0 + r1) * ldW + k0;

  f32x4 acc00 = {0.f,0.f,0.f,0.f}, acc01 = {0.f,0.f,0.f,0.f};
  f32x4 acc10 = {0.f,0.f,0.f,0.f}, acc11 = {0.f,0.f,0.f,0.f};

  { // stage chunk 0 -> buf 0
    bf16x8 a0 = load8(Arow0 + c0*8);
    bf16x8 a1 = load8(Arow1 + c0*8);
    bf16x8 b0 = load8(Wrow0 + c0*8);
    bf16x8 b1 = load8(Wrow1 + c0*8);
    *(bf16x8*)(As0 + r0*64 + sw0) = a0;
    *(bf16x8*)(As0 + r1*64 + sw1) = a1;
    *(bf16x8*)(Bs0 + r0*64 + sw0) = b0;
    *(bf16x8*)(Bs0 + r1*64 + sw1) = b1;
  }
  for (int kc = 0; kc < 16; ++kc) {
    const int cur = (kc & 1) * 4096;
    const int nxt = 4096 - cur;
    __syncthreads();                       // buf[cur] staged & buf[nxt] drained
    bf16x8 a0, a1, b0, b1;
    const bool pf = (kc < 15);
    if (pf) {
      const int off = (kc+1)*64 + c0*8;
      a0 = load8(Arow0 + off);
      a1 = load8(Arow1 + off);
      b0 = load8(Wrow0 + off);
      b1 = load8(Wrow1 + off);
    }
    const u16* Ac = As0 + cur;
    const u16* Bc = Bs0 + cur;
    #pragma unroll
    for (int ks = 0; ks < 2; ++ks) {
      const int sa = ((ks*4 + l4) ^ swzr) * 8;
      bf16x8 af0 = *(const bf16x8*)(Ac + (wm + l15)*64      + sa);
      bf16x8 af1 = *(const bf16x8*)(Ac + (wm + 16 + l15)*64 + sa);
      bf16x8 bf0 = *(const bf16x8*)(Bc + (wn + l15)*64      + sa);
      bf16x8 bf1 = *(const bf16x8*)(Bc + (wn + 16 + l15)*64 + sa);
      acc00 = __builtin_amdgcn_mfma_f32_16x16x32_bf16(af0, bf0, acc00, 0,0,0);
      acc01 = __builtin_amdgcn_mfma_f32_16x16x32_bf16(af0, bf1, acc01, 0,0,0);
      acc10 = __builtin_amdgcn_mfma_f32_16x16x32_bf16(af1, bf0, acc10, 0,0,0);
      acc11 = __builtin_amdgcn_mfma_f32_16x16x32_bf16(af1, bf1, acc11, 0,0,0);
    }
    if (pf) {
      u16* An = As0 + nxt; u16* Bn = Bs0 + nxt;
      *(bf16x8*)(An + r0*64 + sw0) = a0;
      *(bf16x8*)(An + r1*64 + sw1) = a1;
      *(bf16x8*)(Bn + r0*64 + sw0) = b0;
      *(bf16x8*)(Bn + r1*64 + sw1) = b1;
    }
  }
  const int nc = n0 + wn + l15;
  #pragma unroll
  for (int sm = 0; sm < 2; ++sm) {
    const int mb = wm + sm*16 + l4*4;
    f32x4 v0 = sm ? acc10 : acc00;
    f32x4 v1 = sm ? acc11 : acc01;
    #pragma unroll
    for (int q = 0; q < 4; ++q) {
      C[(size_t)(mb+q)*G3 + nc]      = v0[q];
      C[(size_t)(mb+q)*G3 + nc + 16] = v1[q];
    }
  }
}

// ---- combine global GRU: g_t = GRU(GIGa+GIGb, GHG; g_{t-1}); emits score_t ----
__device__ void combineG(const DPar& p, int t, int cb) {
  const int gt = cb*256 + (int)threadIdx.x;
  const int b  = gt >> 5;
  const int j0 = (gt & 31) << 5;
  const float* GA = p.GIGa + (size_t)b*G3;
  const float* GB = p.GIGb + (size_t)b*G3;
  const float* GH = p.GHG  + (size_t)b*G3;
  float sc = 0.f;
  for (int jj = 0; jj < 32; ++jj) {
    const int j = j0 + jj;
    float ir = GA[j]      + p.bihg[j];
    float iz = GA[1024+j] + p.bihg[1024+j];
    float in_= GA[2048+j] + p.bihg[2048+j];
    float hr = p.bhhg[j], hz = p.bhhg[1024+j], hn = p.bhhg[2048+j];
    if (t > 0) {
      ir += GB[j]; iz += GB[1024+j]; in_ += GB[2048+j];
      hr += GH[j]; hz += GH[1024+j]; hn  += GH[2048+j];
    }
    float r = sigm(ir + hr);
    float z = sigm(iz + hz);
    float n = tanh_(in_ + r*hn);
    float g = (1.f - z)*n + z * p.gf[b*DD + j];
    p.gf[b*DD + j] = g;
    p.ghist[(size_t)t*BB*DD + b*DD + j] = f2b(g);
    sc += g * p.watt[j];
  }
  #pragma unroll
  for (int o = 1; o < 32; o <<= 1) sc += __shfl_xor(sc, o, 64);
  if ((threadIdx.x & 31) == 0) p.scores[t*BB + b] = sc;   // single writer per (t,b)
}

// ---- combine emotion GRU for step td; writes output row td ----
__device__ void combineE(const DPar& p, int td, int cb) {
  const int gt = cb*256 + (int)threadIdx.x;
  const int b  = gt >> 5;
  const int j0 = (gt & 31) << 5;
  const float* GI = p.GIE + (size_t)b*G3;
  const float* GH = p.GHE + (size_t)b*G3;
  for (int jj = 0; jj < 32; ++jj) {
    const int j = j0 + jj;
    float ir = GI[j]      + p.bihe[j];
    float iz = GI[1024+j] + p.bihe[1024+j];
    float in_= GI[2048+j] + p.bihe[2048+j];
    float hr = p.bhhe[j], hz = p.bhhe[1024+j], hn = p.bhhe[2048+j];
    if (td > 0) { hr += GH[j]; hz += GH[1024+j]; hn += GH[2048+j]; }
    float r = sigm(ir + hr);
    float z = sigm(iz + hz);
    float n = tanh_(in_ + r*hn);
    float h = p.ef[b*DD + j];
    float e = (1.f - z)*n + z*h;
    p.ef[b*DD + j] = e;
    p.eb[b*DD + j] = f2b(e);
    p.out[(size_t)td*BB*DD + b*DD + j] = e;
  }
}

// ---- combine party GRU: update speaker slot of parties; emit q_sel(t+1) ----
__device__ void combineQ(const DPar& p, int t, int cb) {
  const int gt = cb*256 + (int)threadIdx.x;
  const int b  = gt >> 6;
  const int j0 = (gt & 63) << 4;
  const int spkc = p.spk[t*BB + b];
  const int spkn = (t+1 < TT) ? p.spk[(t+1)*BB + b] : spkc;
  const float* GA = p.GIPa + (size_t)b*G3;
  const float* GB = p.GIPb + (size_t)b*G3;
  const float* GH = p.GHP  + (size_t)b*G3;
  for (int jj = 0; jj < 16; ++jj) {
    const int j = j0 + jj;
    float ir = GA[j]      + p.bihp[j];
    float iz = GA[1024+j] + p.bihp[1024+j];
    float in_= GA[2048+j] + p.bihp[2048+j];
    float hr = p.bhhp[j], hz = p.bhhp[1024+j], hn = p.bhhp[2048+j];
    if (t > 0) {
      ir += GB[j]; iz += GB[1024+j]; in_ += GB[2048+j];
      hr += GH[j]; hz += GH[1024+j]; hn  += GH[2048+j];
    }
    float r = sigm(ir + hr);
    float z = sigm(iz + hz);
    float n = tanh_(in_ + r*hn);
    float h = p.parties[(size_t)(b*2 + spkc)*DD + j];
    float q = (1.f - z)*n + z*h;
    p.parties[(size_t)(b*2 + spkc)*DD + j] = q;
    p.qnewb[b*DD + j] = f2b(q);
    float qn = (spkn == spkc) ? q : p.parties[(size_t)(b*2 + spkn)*DD + j];
    p.qselb[b*DD + j] = f2b(qn);
  }
}

// ---- attention: c_{t+1} = softmax(scores[0..t]) . ghist[0..t] ----
__device__ void attn(const DPar& p, int t, int ab) {
  const int nl = ab*32 + ((int)threadIdx.x & 31);
  const int b0 = (int)threadIdx.x >> 5;
  for (int b = b0; b < BB; b += 8) {
    float m = -1e30f;
    for (int u = 0; u <= t; ++u) m = fmaxf(m, p.scores[u*BB + b]);
    float s = 0.f;
    for (int u = 0; u <= t; ++u) s += __expf(p.scores[u*BB + b] - m);
    float inv = 1.f / s;
    float acc = 0.f;
    for (int u = 0; u <= t; ++u)
      acc += __expf(p.scores[u*BB + b] - m) * b2f(p.ghist[(size_t)u*BB*DD + b*DD + nl]);
    p.cb[b*DD + nl] = f2b(acc * inv);
  }
}

#define GEMM_W(Abuf, ldA, Wb, Wf, ldW, k0, n0, Cb) \
  do { if constexpr (WB) gemm64(Abuf, ldA, Wb, ldW, k0, n0, Cb, lds); \
       else              gemm64(Abuf, ldA, Wf, ldW, k0, n0, Cb, lds); } while (0)

// ---- persistent cooperative kernel: 128 steps x 3 phases ----
template<bool WB>
__global__ void __launch_bounds__(256, 1) drnn_persist(DPar p) {
  cg::grid_group grid = cg::this_grid();
  __shared__ u16 lds[16384];
  const int blk = blockIdx.x;
  for (int t = 0; t < TT; ++t) {
    const float* featRow = p.feat + (size_t)t*BB*DD;
    // phase A: GIGa | GIGb | GHG | GHP | GIE(t-1)
    if (blk < 48)       GEMM_W(featRow, DD, p.A1, p.Wg, 2048, 0, blk*64, p.GIGa);
    else if (blk < 96)  { if (t) GEMM_W(p.qselb, DD, p.A1, p.Wg, 2048, 1024, (blk-48)*64, p.GIGb); }
    else if (blk < 144) { if (t) GEMM_W(p.ghist + (size_t)(t-1)*BB*DD, DD, p.A2, p.Whg, 1024, 0, (blk-96)*64, p.GHG); }
    else if (blk < 192) { if (t) GEMM_W(p.qselb, DD, p.A4, p.Whp, 1024, 0, (blk-144)*64, p.GHP); }
    else                { if (t) GEMM_W(p.qnewb, DD, p.A5, p.We, 1024, 0, (blk-192)*64, p.GIE); }
    grid.sync();
    // phase B: GIPa | GIPb | combine-G | combine-E(t-1)
    if (blk < 48)       GEMM_W(featRow, DD, p.A3, p.Wp, 2048, 0, blk*64, p.GIPa);
    else if (blk < 96)  { if (t) GEMM_W(p.cb, DD, p.A3, p.Wp, 2048, 1024, (blk-48)*64, p.GIPb); }
    else if (blk < 104) combineG(p, t, blk-96);
    else if (blk < 112) { if (t) combineE(p, t-1, blk-104); }
    grid.sync();
    // phase C: GHE | attn -> c(t+1) | combine-Q
    if (blk < 48)       { if (t) GEMM_W(p.eb, DD, p.A6, p.Whe, 1024, 0, blk*64, p.GHE); }
    else if (blk < 80)  { if (t+1 < TT) attn(p, t, blk-48); }
    else if (blk < 96)  combineQ(p, t, blk-80);
    grid.sync();
  }
  // epilogue: GIE(127), then combine-E(127)
  if (blk >= 192) GEMM_W(p.qnewb, DD, p.A5, p.We, 1024, 0, (blk-192)*64, p.GIE);
  grid.sync();
  if (blk < 8) combineE(p, TT-1, blk);
}

// ---- weight fp32 -> bf16 cast (full mode only) ----
__global__ void convertK(const float* __restrict__ Wg, const float* __restrict__ Whg,
                         const float* __restrict__ Wp, const float* __restrict__ Whp,
                         const float* __restrict__ We, const float* __restrict__ Whe,
                         u16* A1, u16* A2, u16* A3, u16* A4, u16* A5, u16* A6) {
  const long n1 = (long)G3*2048/4, n2 = (long)G3*1024/4;
  const long tot = 2*n1 + 4*n2;
  long gid = (long)blockIdx.x*256 + threadIdx.x;
  const long stride = (long)gridDim.x*256;
  for (long i = gid; i < tot; i += stride) {
    const float* src; u16* dst; long o = i;
    if (o < n1) { src = Wg;  dst = A1; }
    else { o -= n1;
      if (o < n2) { src = Whg; dst = A2; }
      else { o -= n2;
        if (o < n1) { src = Wp; dst = A3; }
        else { o -= n1;
          if (o < n2) { src = Whp; dst = A4; }
          else { o -= n2;
            if (o < n2) { src = We; dst = A5; }
            else { o -= n2; src = Whe; dst = A6; }
          }
        }
      }
    }
    f32x4 v = *(const f32x4*)(src + o*4);
    s16x4 w;
    w[0] = (short)f2b(v[0]); w[1] = (short)f2b(v[1]);
    w[2] = (short)f2b(v[2]); w[3] = (short)f2b(v[3]);
    *(s16x4*)(dst + o*4) = w;
  }
}

// ---- zero state + extract speaker index (runs every launch; poison-safe) ----
__global__ void initK(float* parties, float* gf, float* ef, float* scores,
                      u16* cb, u16* qselb, u16* qnewb, u16* eb,
                      const float* spkOH, int* spk) {
  const int i = blockIdx.x*256 + threadIdx.x;
  if (i < BB*2*DD) parties[i] = 0.f;
  if (i < BB*DD) { gf[i] = 0.f; ef[i] = 0.f; cb[i] = 0; qselb[i] = 0; qnewb[i] = 0; eb[i] = 0; }
  if (i < TT*BB) { scores[i] = 0.f; spk[i] = (spkOH[(size_t)i*2 + 1] > 0.5f) ? 1 : 0; }
}

extern "C" void kernel_launch(void* const* d_in, const int* in_sizes, int n_in,
                              void* d_out, int out_size, void* d_ws, size_t ws_size,
                              hipStream_t stream) {
  const float* feat  = (const float*)d_in[0];
  const float* spkOH = (const float*)d_in[1];
  const float* Wih_g = (const float*)d_in[2];
  const float* Whh_g = (const float*)d_in[3];
  const float* bih_g = (const float*)d_in[4];
  const float* bhh_g = (const float*)d_in[5];
  const float* Wih_p = (const float*)d_in[6];
  const float* Whh_p = (const float*)d_in[7];
  const float* bih_p = (const float*)d_in[8];
  const float* bhh_p = (const float*)d_in[9];
  const float* Wih_e = (const float*)d_in[10];
  const float* Whh_e = (const float*)d_in[11];
  const float* bih_e = (const float*)d_in[12];
  const float* bhh_e = (const float*)d_in[13];
  const float* watt  = (const float*)d_in[14];

  char* w = (char*)d_ws;
  auto alloc = [&](size_t bytes) -> char* {
    char* r = w; w += (bytes + 255) & ~(size_t)255; return r;
  };
  // --- state region (always required) ---
  u16* ghist = (u16*)alloc((size_t)TT*BB*DD*2);
  float* scores = (float*)alloc((size_t)TT*BB*4);
  u16* cb    = (u16*)alloc((size_t)BB*DD*2);
  u16* qselb = (u16*)alloc((size_t)BB*DD*2);
  u16* qnewb = (u16*)alloc((size_t)BB*DD*2);
  u16* eb    = (u16*)alloc((size_t)BB*DD*2);
  float* parties = (float*)alloc((size_t)BB*2*DD*4);
  float* gf  = (float*)alloc((size_t)BB*DD*4);
  float* ef  = (float*)alloc((size_t)BB*DD*4);
  float* GIGa = (float*)alloc((size_t)BB*G3*4);
  float* GIGb = (float*)alloc((size_t)BB*G3*4);
  float* GHG  = (float*)alloc((size_t)BB*G3*4);
  float* GHP  = (float*)alloc((size_t)BB*G3*4);
  float* GIE  = (float*)alloc((size_t)BB*G3*4);
  float* GIPa = (float*)alloc((size_t)BB*G3*4);
  float* GIPb = (float*)alloc((size_t)BB*G3*4);
  float* GHE  = (float*)alloc((size_t)BB*G3*4);
  int* spk    = (int*)alloc((size_t)TT*BB*4);
  const size_t state_need = (size_t)(w - (char*)d_ws);
  // --- bf16 weight region (full mode only) ---
  u16* A1 = (u16*)alloc((size_t)G3*2048*2);
  u16* A2 = (u16*)alloc((size_t)G3*1024*2);
  u16* A3 = (u16*)alloc((size_t)G3*2048*2);
  u16* A4 = (u16*)alloc((size_t)G3*1024*2);
  u16* A5 = (u16*)alloc((size_t)G3*1024*2);
  u16* A6 = (u16*)alloc((size_t)G3*1024*2);
  const size_t full_need = (size_t)(w - (char*)d_ws);

  if (ws_size < state_need) return;  // cannot run safely; fail validation w/o fault
  const bool full = (ws_size >= full_need);

  if (full)
    hipLaunchKernelGGL(convertK, dim3(2048), dim3(256), 0, stream,
                       Wih_g, Whh_g, Wih_p, Whh_p, Wih_e, Whh_e,
                       A1, A2, A3, A4, A5, A6);
  hipLaunchKernelGGL(initK, dim3(512), dim3(256), 0, stream,
                     parties, gf, ef, scores, cb, qselb, qnewb, eb, spkOH, spk);

  DPar p;
  p.Wg = Wih_g; p.Whg = Whh_g; p.Wp = Wih_p; p.Whp = Whh_p; p.We = Wih_e; p.Whe = Whh_e;
  p.A1 = A1; p.A2 = A2; p.A3 = A3; p.A4 = A4; p.A5 = A5; p.A6 = A6;
  p.feat = feat;
  p.ghist = ghist; p.cb = cb; p.qselb = qselb; p.qnewb = qnewb; p.eb = eb;
  p.scores = scores; p.parties = parties; p.gf = gf; p.ef = ef;
  p.GIGa = GIGa; p.GIGb = GIGb; p.GHG = GHG; p.GHP = GHP; p.GIE = GIE;
  p.GIPa = GIPa; p.GIPb = GIPb; p.GHE = GHE;
  p.bihg = bih_g; p.bhhg = bhh_g; p.bihp = bih_p; p.bhhp = bhh_p;
  p.bihe = bih_e; p.bhhe = bhh_e; p.watt = watt;
  p.spk = spk; p.out = (float*)d_out;

  void* args[] = { &p };
  if (full)
    hipLaunchCooperativeKernel((void*)drnn_persist<true>,  dim3(NBLK), dim3(256), args, 0, stream);
  else
    hipLaunchCooperativeKernel((void*)drnn_persist<false>, dim3(NBLK), dim3(256), args, 0, stream);
}